// Round 4
// baseline (790.049 us; speedup 1.0000x reference)
//
#include <hip/hip_runtime.h>
#include <hip/hip_bf16.h>

// ---------------------------------------------------------------------------
// AfmoE MoE: routing (sigmoid top-8) + 16 routed SwiGLU experts + shared
// expert as expert #16 via gather lists.
// Round 3: barrier-free GEMMs. A and B MFMA fragments are loaded directly
// global->VGPR (one 16B chunk per lane matches the fragment layout), so the
// K-loop has NO __syncthreads and the compiler pipelines loads with
// fine-grained vmcnt. Weight reuse is served by L2/L3 (bf16 pool ~102 MB).
// ---------------------------------------------------------------------------

typedef __attribute__((ext_vector_type(8))) short bf16x8;
typedef __attribute__((ext_vector_type(4))) float f32x4;

#define NTOK 1024   // B*S
#define DD   1024   // hidden
#define II   1024   // intermediate (same for shared)
#define NE   16     // routed experts
#define NEXP 17     // + shared expert as index 16
#define KSEL 8
#define RSCALE 2.826f

// fallback-path tiling
#define BM 128
#define BN 64
#define BK 32
#define LDA 40

// workspace layout (bytes)
#define MB (1024ull*1024ull)
#define OFF_XBF   0ull                         // ushort[NTOK*DD]          2 MiB
#define OFF_H     (2ull*MB)                    // ushort[NEXP*NTOK*II]    34 MiB
#define OFF_WG    (36ull*MB)                   // ushort[NEXP*II*DD]      34 MiB
#define OFF_WU    (70ull*MB)                   // ushort[NEXP*II*DD]      34 MiB
#define OFF_WD    (104ull*MB)                  // ushort[NEXP*DD*II]      34 MiB
#define OFF_LIST  (138ull*MB)                  // int[NEXP*NTOK]
#define OFF_SCALE (OFF_LIST + 4ull*NEXP*NTOK)  // float[NEXP*NTOK]
#define OFF_CNT   (OFF_SCALE + 4ull*NEXP*NTOK) // int[NEXP]
#define WS_NEED   (OFF_CNT + 4096ull)

__device__ __forceinline__ unsigned short f2bf(float f) {
    union { __hip_bfloat16 h; unsigned short u; } c;
    c.h = __float2bfloat16(f);
    return c.u;
}

// --- convert x to bf16; init shared-expert list/scale/count -----------------
__global__ __launch_bounds__(256) void prep_kernel(
    const float* __restrict__ x, unsigned short* __restrict__ xbf,
    int* __restrict__ list, float* __restrict__ scalebuf, int* __restrict__ count)
{
    int idx = blockIdx.x * 256 + threadIdx.x;
    float4 v = ((const float4*)x)[idx];
    ((ushort4*)xbf)[idx] = make_ushort4(f2bf(v.x), f2bf(v.y), f2bf(v.z), f2bf(v.w));
    if (idx < NTOK) { list[NE * NTOK + idx] = idx; scalebuf[NE * NTOK + idx] = 1.0f; }
    if (idx == 0) count[NE] = NTOK;
}

// --- convert all expert weights fp32 -> bf16 pools -------------------------
__global__ __launch_bounds__(256) void wconv_kernel(
    const float* __restrict__ wg, const float* __restrict__ wu, const float* __restrict__ wd,
    const float* __restrict__ sgw, const float* __restrict__ suw, const float* __restrict__ sdw,
    unsigned short* __restrict__ wgb, unsigned short* __restrict__ wub,
    unsigned short* __restrict__ wdb)
{
    size_t i4 = (size_t)blockIdx.x * 256 + threadIdx.x;
    const size_t ROUTED4 = (size_t)NE * II * DD / 4;
    int p = blockIdx.y;
    const float* rsrc = (p == 0) ? wg : (p == 1) ? wu : wd;
    const float* ssrc = (p == 0) ? sgw : (p == 1) ? suw : sdw;
    unsigned short* dst = (p == 0) ? wgb : (p == 1) ? wub : wdb;
    const float* src = (i4 < ROUTED4) ? rsrc + 4 * i4 : ssrc + 4 * (i4 - ROUTED4);
    float4 v = *(const float4*)src;
    ((ushort4*)dst)[i4] = make_ushort4(f2bf(v.x), f2bf(v.y), f2bf(v.z), f2bf(v.w));
}

// --- routing: one wave per token -------------------------------------------
__global__ __launch_bounds__(64) void routing_kernel(
    const float* __restrict__ x, const float* __restrict__ gw,
    const float* __restrict__ bias, int* __restrict__ count,
    int* __restrict__ list, float* __restrict__ scalebuf)
{
    int t = blockIdx.x, lane = threadIdx.x;
    float acc[NE];
#pragma unroll
    for (int e = 0; e < NE; e++) acc[e] = 0.f;
    const float* xr = x + (size_t)t * DD;
    for (int i = 0; i < DD / 64; i++) {
        float xv = xr[lane + 64 * i];
#pragma unroll
        for (int e = 0; e < NE; e++) acc[e] += xv * gw[e * DD + lane + 64 * i];
    }
#pragma unroll
    for (int e = 0; e < NE; e++) {
        float v = acc[e];
        for (int off = 32; off > 0; off >>= 1) v += __shfl_xor(v, off, 64);
        acc[e] = v;
    }
    if (lane == 0) {
        float sc[NE], sel[NE];
#pragma unroll
        for (int e = 0; e < NE; e++) {
            sc[e] = 1.f / (1.f + expf(-acc[e]));
            sel[e] = sc[e] + bias[e];
        }
        bool used[NE] = {};
        int inds[KSEL];
        float ssum = 0.f;
        for (int k = 0; k < KSEL; k++) {
            float best = -1e30f; int bi = 0;
            for (int e = 0; e < NE; e++)
                if (!used[e] && sel[e] > best) { best = sel[e]; bi = e; }
            used[bi] = true; inds[k] = bi; ssum += sc[bi];
        }
        float inv = RSCALE / ssum;
        for (int k = 0; k < KSEL; k++) {
            int e = inds[k];
            int pos = atomicAdd(&count[e], 1);
            list[e * NTOK + pos] = t;
            scalebuf[e * NTOK + pos] = sc[e] * inv;
        }
    }
}

// --- barrier-free fused gate+up GEMM ---------------------------------------
// grid (16, 8, NEXP), block 256 = 4 independent waves.
// wave tile: 64M x 32N, both G and U accumulated (16 MFMA + 8 loads / K-step).
__global__ __launch_bounds__(256) void gateup_kernel(
    const unsigned short* __restrict__ xbf,
    const unsigned short* __restrict__ wgb, const unsigned short* __restrict__ wub,
    const int* __restrict__ count, const int* __restrict__ list,
    const float* __restrict__ scalebuf, unsigned short* __restrict__ hbuf)
{
    int e = blockIdx.z;
    int cnt = count[e];
    int m0 = blockIdx.x * 64;
    if (m0 >= cnt) return;
    int tid = threadIdx.x;
    int lane = tid & 63, wave = tid >> 6;
    int n0 = (blockIdx.y * 4 + wave) * 32;
    int row16 = lane & 15, quad = lane >> 4;

    const unsigned short* Bg = wgb + (size_t)e * II * DD;
    const unsigned short* Bu = wub + (size_t)e * II * DD;

    // A-fragment row pointers (gathered tokens; rows >= cnt clamp -> garbage
    // lands only in C rows we skip at the epilogue)
    const unsigned short* pA[4];
#pragma unroll
    for (int mi = 0; mi < 4; mi++) {
        int gr = m0 + mi * 16 + row16;
        int idx = (gr < cnt) ? gr : (cnt - 1);
        pA[mi] = xbf + (size_t)list[e * NTOK + idx] * DD + quad * 8;
    }
    const unsigned short* pBg[2];
    const unsigned short* pBu[2];
#pragma unroll
    for (int ni = 0; ni < 2; ni++) {
        int n = n0 + ni * 16 + row16;
        pBg[ni] = Bg + (size_t)n * DD + quad * 8;
        pBu[ni] = Bu + (size_t)n * DD + quad * 8;
    }

    f32x4 accG[4][2], accU[4][2];
#pragma unroll
    for (int mi = 0; mi < 4; mi++)
#pragma unroll
        for (int ni = 0; ni < 2; ni++) {
            accG[mi][ni] = (f32x4){0.f, 0.f, 0.f, 0.f};
            accU[mi][ni] = (f32x4){0.f, 0.f, 0.f, 0.f};
        }

#pragma unroll 4
    for (int k0 = 0; k0 < DD; k0 += 32) {
        bf16x8 a[4], bg[2], bu[2];
#pragma unroll
        for (int mi = 0; mi < 4; mi++) a[mi] = *(const bf16x8*)(pA[mi] + k0);
#pragma unroll
        for (int ni = 0; ni < 2; ni++) {
            bg[ni] = *(const bf16x8*)(pBg[ni] + k0);
            bu[ni] = *(const bf16x8*)(pBu[ni] + k0);
        }
#pragma unroll
        for (int mi = 0; mi < 4; mi++)
#pragma unroll
            for (int ni = 0; ni < 2; ni++) {
                accG[mi][ni] = __builtin_amdgcn_mfma_f32_16x16x32_bf16(a[mi], bg[ni], accG[mi][ni], 0, 0, 0);
                accU[mi][ni] = __builtin_amdgcn_mfma_f32_16x16x32_bf16(a[mi], bu[ni], accU[mi][ni], 0, 0, 0);
            }
    }

    // epilogue: silu(g)*u * route_scale -> bf16 h
#pragma unroll
    for (int mi = 0; mi < 4; mi++) {
        int grb = m0 + mi * 16 + quad * 4;
#pragma unroll
        for (int r = 0; r < 4; r++) {
            int gr = grb + r;
            if (gr >= cnt) continue;
            float rs = scalebuf[e * NTOK + gr];
            size_t rowoff = ((size_t)e * NTOK + gr) * II + n0;
#pragma unroll
            for (int ni = 0; ni < 2; ni++) {
                float g = accG[mi][ni][r], u = accU[mi][ni][r];
                float h = g / (1.f + __expf(-g)) * u * rs;
                hbuf[rowoff + ni * 16 + row16] = f2bf(h);
            }
        }
    }
}

// --- barrier-free down GEMM: y[tok] += h Wd^T (atomic scatter) --------------
// grid (16, 4, NEXP), block 256 = 4 independent waves; wave tile 64M x 64N.
__global__ __launch_bounds__(256) void down_kernel(
    const unsigned short* __restrict__ hbuf,
    const unsigned short* __restrict__ wdb,
    const int* __restrict__ count, const int* __restrict__ list,
    float* __restrict__ y)
{
    int e = blockIdx.z;
    int cnt = count[e];
    int m0 = blockIdx.x * 64;
    if (m0 >= cnt) return;
    int tid = threadIdx.x;
    int lane = tid & 63, wave = tid >> 6;
    int n0 = (blockIdx.y * 4 + wave) * 64;
    int row16 = lane & 15, quad = lane >> 4;

    const unsigned short* Bp = wdb + (size_t)e * DD * II;

    const unsigned short* pA[4];
#pragma unroll
    for (int mi = 0; mi < 4; mi++) {
        int gr = m0 + mi * 16 + row16;
        int idx = (gr < cnt) ? gr : (cnt - 1);
        pA[mi] = hbuf + ((size_t)e * NTOK + idx) * II + quad * 8;
    }
    const unsigned short* pB[4];
#pragma unroll
    for (int ni = 0; ni < 4; ni++)
        pB[ni] = Bp + (size_t)(n0 + ni * 16 + row16) * II + quad * 8;

    f32x4 acc[4][4];
#pragma unroll
    for (int mi = 0; mi < 4; mi++)
#pragma unroll
        for (int ni = 0; ni < 4; ni++) acc[mi][ni] = (f32x4){0.f, 0.f, 0.f, 0.f};

#pragma unroll 4
    for (int k0 = 0; k0 < II; k0 += 32) {
        bf16x8 a[4], b[4];
#pragma unroll
        for (int mi = 0; mi < 4; mi++) a[mi] = *(const bf16x8*)(pA[mi] + k0);
#pragma unroll
        for (int ni = 0; ni < 4; ni++) b[ni] = *(const bf16x8*)(pB[ni] + k0);
#pragma unroll
        for (int mi = 0; mi < 4; mi++)
#pragma unroll
            for (int ni = 0; ni < 4; ni++)
                acc[mi][ni] = __builtin_amdgcn_mfma_f32_16x16x32_bf16(a[mi], b[ni], acc[mi][ni], 0, 0, 0);
    }

#pragma unroll
    for (int mi = 0; mi < 4; mi++) {
        int grb = m0 + mi * 16 + quad * 4;
#pragma unroll
        for (int r = 0; r < 4; r++) {
            int gr = grb + r;
            if (gr >= cnt) continue;
            int t = list[e * NTOK + gr];
            float* yr = y + (size_t)t * DD + n0;
#pragma unroll
            for (int ni = 0; ni < 4; ni++)
                unsafeAtomicAdd(yr + ni * 16 + row16, acc[mi][ni][r]);
        }
    }
}

// ======================= fallback path (round-0 kernels) ====================
__global__ __launch_bounds__(256) void gateup_fb(
    const unsigned short* __restrict__ xbf,
    const float* __restrict__ wg, const float* __restrict__ wu,
    const float* __restrict__ sgw, const float* __restrict__ suw,
    const int* __restrict__ count, const int* __restrict__ list,
    const float* __restrict__ scalebuf, unsigned short* __restrict__ hbuf)
{
    int e = blockIdx.z;
    int cnt = count[e];
    int m0 = blockIdx.x * BM;
    if (m0 >= cnt) return;
    int n0 = blockIdx.y * BN;
    const float* Bg = (e < NE) ? wg + (size_t)e * II * DD : sgw;
    const float* Bu = (e < NE) ? wu + (size_t)e * II * DD : suw;

    __shared__ __align__(16) unsigned short As[BM * LDA];
    __shared__ __align__(16) unsigned short Bgs[BN * LDA];
    __shared__ __align__(16) unsigned short Bus[BN * LDA];
    __shared__ int rowtok[BM];

    int tid = threadIdx.x;
    if (tid < BM) {
        int gr = m0 + tid;
        rowtok[tid] = (gr < cnt) ? list[e * NTOK + gr] : -1;
    }
    __syncthreads();

    int lane = tid & 63, wave = tid >> 6;
    int wm = wave >> 1, wn = wave & 1;
    int row16 = lane & 15, quad = lane >> 4;

    f32x4 accG[4][2], accU[4][2];
#pragma unroll
    for (int mi = 0; mi < 4; mi++)
#pragma unroll
        for (int ni = 0; ni < 2; ni++) {
            accG[mi][ni] = (f32x4){0.f, 0.f, 0.f, 0.f};
            accU[mi][ni] = (f32x4){0.f, 0.f, 0.f, 0.f};
        }

    for (int k0 = 0; k0 < DD; k0 += BK) {
#pragma unroll
        for (int i = 0; i < 2; i++) {
            int c = tid + 256 * i;
            int row = c >> 2, kc = (c & 3) * 8;
            int tok = rowtok[row];
            uint4 v = (tok >= 0) ? *(const uint4*)(xbf + (size_t)tok * DD + k0 + kc)
                                 : make_uint4(0u, 0u, 0u, 0u);
            *(uint4*)(As + row * LDA + kc) = v;
        }
#pragma unroll
        for (int i = 0; i < 2; i++) {
            int c = tid + 256 * i;
            int row = c >> 3, f = (c & 7) * 4;
            float4 vg = *(const float4*)(Bg + (size_t)(n0 + row) * DD + k0 + f);
            float4 vu = *(const float4*)(Bu + (size_t)(n0 + row) * DD + k0 + f);
            *(ushort4*)(Bgs + row * LDA + f) = make_ushort4(f2bf(vg.x), f2bf(vg.y), f2bf(vg.z), f2bf(vg.w));
            *(ushort4*)(Bus + row * LDA + f) = make_ushort4(f2bf(vu.x), f2bf(vu.y), f2bf(vu.z), f2bf(vu.w));
        }
        __syncthreads();

        bf16x8 af[4], bg[2], bu[2];
#pragma unroll
        for (int mi = 0; mi < 4; mi++)
            af[mi] = *(const bf16x8*)(As + (wm * 64 + mi * 16 + row16) * LDA + quad * 8);
#pragma unroll
        for (int ni = 0; ni < 2; ni++) {
            bg[ni] = *(const bf16x8*)(Bgs + (wn * 32 + ni * 16 + row16) * LDA + quad * 8);
            bu[ni] = *(const bf16x8*)(Bus + (wn * 32 + ni * 16 + row16) * LDA + quad * 8);
        }
#pragma unroll
        for (int mi = 0; mi < 4; mi++)
#pragma unroll
            for (int ni = 0; ni < 2; ni++) {
                accG[mi][ni] = __builtin_amdgcn_mfma_f32_16x16x32_bf16(af[mi], bg[ni], accG[mi][ni], 0, 0, 0);
                accU[mi][ni] = __builtin_amdgcn_mfma_f32_16x16x32_bf16(af[mi], bu[ni], accU[mi][ni], 0, 0, 0);
            }
        __syncthreads();
    }

#pragma unroll
    for (int mi = 0; mi < 4; mi++) {
        int mbase = wm * 64 + mi * 16 + quad * 4;
#pragma unroll
        for (int r = 0; r < 4; r++) {
            int gr = m0 + mbase + r;
            if (gr >= cnt) continue;
            float rs = scalebuf[e * NTOK + gr];
            size_t rowoff = ((size_t)e * NTOK + gr) * II + n0;
#pragma unroll
            for (int ni = 0; ni < 2; ni++) {
                int n = wn * 32 + ni * 16 + row16;
                float g = accG[mi][ni][r], u = accU[mi][ni][r];
                float h = g / (1.f + __expf(-g)) * u * rs;
                hbuf[rowoff + n] = f2bf(h);
            }
        }
    }
}

__global__ __launch_bounds__(256) void down_fb(
    const unsigned short* __restrict__ hbuf,
    const float* __restrict__ wd, const float* __restrict__ sdw,
    const int* __restrict__ count, const int* __restrict__ list,
    float* __restrict__ y)
{
    int e = blockIdx.z;
    int cnt = count[e];
    int m0 = blockIdx.x * BM;
    if (m0 >= cnt) return;
    int n0 = blockIdx.y * BN;
    const float* Bp = (e < NE) ? wd + (size_t)e * DD * II : sdw;

    __shared__ __align__(16) unsigned short As[BM * LDA];
    __shared__ __align__(16) unsigned short Bs[BN * LDA];

    int tid = threadIdx.x;
    int lane = tid & 63, wave = tid >> 6;
    int wm = wave >> 1, wn = wave & 1;
    int row16 = lane & 15, quad = lane >> 4;

    f32x4 acc[4][2];
#pragma unroll
    for (int mi = 0; mi < 4; mi++)
#pragma unroll
        for (int ni = 0; ni < 2; ni++) acc[mi][ni] = (f32x4){0.f, 0.f, 0.f, 0.f};

    const unsigned short* Abase = hbuf + ((size_t)e * NTOK + m0) * II;

    for (int k0 = 0; k0 < II; k0 += BK) {
#pragma unroll
        for (int i = 0; i < 2; i++) {
            int c = tid + 256 * i;
            int row = c >> 2, kc = (c & 3) * 8;
            uint4 v = (m0 + row < cnt) ? *(const uint4*)(Abase + (size_t)row * II + k0 + kc)
                                       : make_uint4(0u, 0u, 0u, 0u);
            *(uint4*)(As + row * LDA + kc) = v;
        }
#pragma unroll
        for (int i = 0; i < 2; i++) {
            int c = tid + 256 * i;
            int row = c >> 3, f = (c & 7) * 4;
            float4 v = *(const float4*)(Bp + (size_t)(n0 + row) * II + k0 + f);
            *(ushort4*)(Bs + row * LDA + f) = make_ushort4(f2bf(v.x), f2bf(v.y), f2bf(v.z), f2bf(v.w));
        }
        __syncthreads();

        bf16x8 af[4], bf[2];
#pragma unroll
        for (int mi = 0; mi < 4; mi++)
            af[mi] = *(const bf16x8*)(As + (wm * 64 + mi * 16 + row16) * LDA + quad * 8);
#pragma unroll
        for (int ni = 0; ni < 2; ni++)
            bf[ni] = *(const bf16x8*)(Bs + (wn * 32 + ni * 16 + row16) * LDA + quad * 8);
#pragma unroll
        for (int mi = 0; mi < 4; mi++)
#pragma unroll
            for (int ni = 0; ni < 2; ni++)
                acc[mi][ni] = __builtin_amdgcn_mfma_f32_16x16x32_bf16(af[mi], bf[ni], acc[mi][ni], 0, 0, 0);
        __syncthreads();
    }

#pragma unroll
    for (int mi = 0; mi < 4; mi++) {
        int mbase = wm * 64 + mi * 16 + quad * 4;
#pragma unroll
        for (int r = 0; r < 4; r++) {
            int gr = m0 + mbase + r;
            if (gr >= cnt) continue;
            int t = list[e * NTOK + gr];
#pragma unroll
            for (int ni = 0; ni < 2; ni++) {
                int n = wn * 32 + ni * 16 + row16;
                unsafeAtomicAdd(&y[(size_t)t * DD + n0 + n], acc[mi][ni][r]);
            }
        }
    }
}

extern "C" void kernel_launch(void* const* d_in, const int* in_sizes, int n_in,
                              void* d_out, int out_size, void* d_ws, size_t ws_size,
                              hipStream_t stream)
{
    const float* x    = (const float*)d_in[0];
    const float* gw   = (const float*)d_in[1];
    const float* bias = (const float*)d_in[2];
    const float* wg   = (const float*)d_in[3];
    const float* wu   = (const float*)d_in[4];
    const float* wd   = (const float*)d_in[5];
    const float* sgw  = (const float*)d_in[6];
    const float* suw  = (const float*)d_in[7];
    const float* sdw  = (const float*)d_in[8];
    float* y = (float*)d_out;

    char* ws = (char*)d_ws;
    unsigned short* xbf  = (unsigned short*)(ws + OFF_XBF);
    unsigned short* hbuf = (unsigned short*)(ws + OFF_H);
    unsigned short* wgb  = (unsigned short*)(ws + OFF_WG);
    unsigned short* wub  = (unsigned short*)(ws + OFF_WU);
    unsigned short* wdb  = (unsigned short*)(ws + OFF_WD);
    int*   list     = (int*)(ws + OFF_LIST);
    float* scalebuf = (float*)(ws + OFF_SCALE);
    int*   count    = (int*)(ws + OFF_CNT);

    bool big = (ws_size >= WS_NEED);
    if (!big) {
        list     = (int*)(ws + 36ull * MB);
        scalebuf = (float*)(ws + 36ull * MB + 4ull * NEXP * NTOK);
        count    = (int*)(ws + 36ull * MB + 8ull * NEXP * NTOK);
    }

    hipMemsetAsync(d_out, 0, (size_t)NTOK * DD * sizeof(float), stream);
    hipMemsetAsync(count, 0, NEXP * sizeof(int), stream);

    prep_kernel<<<dim3(NTOK * DD / 4 / 256), 256, 0, stream>>>(x, xbf, list, scalebuf, count);
    routing_kernel<<<dim3(NTOK), 64, 0, stream>>>(x, gw, bias, count, list, scalebuf);

    if (big) {
        wconv_kernel<<<dim3((unsigned)((size_t)NEXP * II * DD / 4 / 256), 3), 256, 0, stream>>>(
            wg, wu, wd, sgw, suw, sdw, wgb, wub, wdb);
        gateup_kernel<<<dim3(16, 8, NEXP), 256, 0, stream>>>(
            xbf, wgb, wub, count, list, scalebuf, hbuf);
        down_kernel<<<dim3(16, 4, NEXP), 256, 0, stream>>>(
            hbuf, wdb, count, list, y);
    } else {
        gateup_fb<<<dim3(NTOK / BM, II / BN, NEXP), 256, 0, stream>>>(
            xbf, wg, wu, sgw, suw, count, list, scalebuf, hbuf);
        down_fb<<<dim3(NTOK / BM, DD / BN, NEXP), 256, 0, stream>>>(
            hbuf, wd, sdw, count, list, y);
    }
}

// Round 5
// 523.485 us; speedup vs baseline: 1.5092x; 1.5092x over previous
//
#include <hip/hip_runtime.h>
#include <hip/hip_bf16.h>

// ---------------------------------------------------------------------------
// AfmoE MoE: routing (sigmoid top-8) + 16 routed SwiGLU experts + shared
// expert as expert #16 via gather lists.
// Round 4: back to the m97-style 2-barrier global_load_lds GEMM (best so
// far), retiled BM=64/BN=64/BK=64 for ~2300 blocks (TLP to hide the barrier
// drain) and half the barrier count. LDS layout [khalf][row][32] keeps the
// wave-uniform staging contract per 32-wide k-half.
// ---------------------------------------------------------------------------

typedef __attribute__((ext_vector_type(8))) short bf16x8;
typedef __attribute__((ext_vector_type(4))) float f32x4;

#define NTOK 1024   // B*S
#define DD   1024   // hidden
#define II   1024   // intermediate (same for shared)
#define NE   16     // routed experts
#define NEXP 17     // + shared expert as index 16
#define KSEL 8
#define RSCALE 2.826f

// fallback-path tiling
#define BM 128
#define BN 64
#define BK 32
#define LDA 40

// workspace layout (bytes)
#define MB (1024ull*1024ull)
#define OFF_XBF   0ull                         // ushort[NTOK*DD]          2 MiB
#define OFF_H     (2ull*MB)                    // ushort[NEXP*NTOK*II]    34 MiB
#define OFF_WG    (36ull*MB)                   // ushort[NEXP*II*DD]      34 MiB
#define OFF_WU    (70ull*MB)                   // ushort[NEXP*II*DD]      34 MiB
#define OFF_WD    (104ull*MB)                  // ushort[NEXP*DD*II]      34 MiB
#define OFF_LIST  (138ull*MB)                  // int[NEXP*NTOK]
#define OFF_SCALE (OFF_LIST + 4ull*NEXP*NTOK)  // float[NEXP*NTOK]
#define OFF_CNT   (OFF_SCALE + 4ull*NEXP*NTOK) // int[NEXP]
#define WS_NEED   (OFF_CNT + 4096ull)

__device__ __forceinline__ unsigned short f2bf(float f) {
    union { __hip_bfloat16 h; unsigned short u; } c;
    c.h = __float2bfloat16(f);
    return c.u;
}

__device__ __forceinline__ void gl2lds16(const unsigned short* g, unsigned short* l) {
    __builtin_amdgcn_global_load_lds(
        (const __attribute__((address_space(1))) void*)g,
        (__attribute__((address_space(3))) void*)l, 16, 0, 0);
}

// --- convert x to bf16; init shared-expert list/scale/count -----------------
__global__ __launch_bounds__(256) void prep_kernel(
    const float* __restrict__ x, unsigned short* __restrict__ xbf,
    int* __restrict__ list, float* __restrict__ scalebuf, int* __restrict__ count)
{
    int idx = blockIdx.x * 256 + threadIdx.x;
    float4 v = ((const float4*)x)[idx];
    ((ushort4*)xbf)[idx] = make_ushort4(f2bf(v.x), f2bf(v.y), f2bf(v.z), f2bf(v.w));
    if (idx < NTOK) { list[NE * NTOK + idx] = idx; scalebuf[NE * NTOK + idx] = 1.0f; }
    if (idx == 0) count[NE] = NTOK;
}

// --- convert all expert weights fp32 -> bf16 pools -------------------------
__global__ __launch_bounds__(256) void wconv_kernel(
    const float* __restrict__ wg, const float* __restrict__ wu, const float* __restrict__ wd,
    const float* __restrict__ sgw, const float* __restrict__ suw, const float* __restrict__ sdw,
    unsigned short* __restrict__ wgb, unsigned short* __restrict__ wub,
    unsigned short* __restrict__ wdb)
{
    size_t i4 = (size_t)blockIdx.x * 256 + threadIdx.x;
    const size_t ROUTED4 = (size_t)NE * II * DD / 4;
    int p = blockIdx.y;
    const float* rsrc = (p == 0) ? wg : (p == 1) ? wu : wd;
    const float* ssrc = (p == 0) ? sgw : (p == 1) ? suw : sdw;
    unsigned short* dst = (p == 0) ? wgb : (p == 1) ? wub : wdb;
    const float* src = (i4 < ROUTED4) ? rsrc + 4 * i4 : ssrc + 4 * (i4 - ROUTED4);
    float4 v = *(const float4*)src;
    ((ushort4*)dst)[i4] = make_ushort4(f2bf(v.x), f2bf(v.y), f2bf(v.z), f2bf(v.w));
}

// --- routing: one wave per token -------------------------------------------
__global__ __launch_bounds__(64) void routing_kernel(
    const float* __restrict__ x, const float* __restrict__ gw,
    const float* __restrict__ bias, int* __restrict__ count,
    int* __restrict__ list, float* __restrict__ scalebuf)
{
    int t = blockIdx.x, lane = threadIdx.x;
    float acc[NE];
#pragma unroll
    for (int e = 0; e < NE; e++) acc[e] = 0.f;
    const float* xr = x + (size_t)t * DD;
    for (int i = 0; i < DD / 64; i++) {
        float xv = xr[lane + 64 * i];
#pragma unroll
        for (int e = 0; e < NE; e++) acc[e] += xv * gw[e * DD + lane + 64 * i];
    }
#pragma unroll
    for (int e = 0; e < NE; e++) {
        float v = acc[e];
        for (int off = 32; off > 0; off >>= 1) v += __shfl_xor(v, off, 64);
        acc[e] = v;
    }
    if (lane == 0) {
        float sc[NE], sel[NE];
#pragma unroll
        for (int e = 0; e < NE; e++) {
            sc[e] = 1.f / (1.f + expf(-acc[e]));
            sel[e] = sc[e] + bias[e];
        }
        bool used[NE] = {};
        int inds[KSEL];
        float ssum = 0.f;
        for (int k = 0; k < KSEL; k++) {
            float best = -1e30f; int bi = 0;
            for (int e = 0; e < NE; e++)
                if (!used[e] && sel[e] > best) { best = sel[e]; bi = e; }
            used[bi] = true; inds[k] = bi; ssum += sc[bi];
        }
        float inv = RSCALE / ssum;
        for (int k = 0; k < KSEL; k++) {
            int e = inds[k];
            int pos = atomicAdd(&count[e], 1);
            list[e * NTOK + pos] = t;
            scalebuf[e * NTOK + pos] = sc[e] * inv;
        }
    }
}

// --- fused gate+up GEMM: BM=64 BN=64 BK=64, 2-barrier K-loop ---------------
// grid (16, 16, NEXP), block 256 = 4 waves, wave tile 32Mx32N (G and U).
__global__ __launch_bounds__(256, 5) void gateup_kernel(
    const unsigned short* __restrict__ xbf,
    const unsigned short* __restrict__ wgb, const unsigned short* __restrict__ wub,
    const int* __restrict__ count, const int* __restrict__ list,
    const float* __restrict__ scalebuf, unsigned short* __restrict__ hbuf)
{
    int e = blockIdx.z;
    int cnt = count[e];
    int m0 = blockIdx.x * 64;
    if (m0 >= cnt) return;
    int n0 = blockIdx.y * 64;
    const unsigned short* Bg = wgb + (size_t)e * II * DD;
    const unsigned short* Bu = wub + (size_t)e * II * DD;

    // LDS: [khalf][row][32 elems] per tile -> 4096 ushorts each
    __shared__ __align__(16) unsigned short As[4096];
    __shared__ __align__(16) unsigned short Bgs[4096];
    __shared__ __align__(16) unsigned short Bus[4096];
    __shared__ int rowtok[64];

    int tid = threadIdx.x;
    if (tid < 64) {
        int gr = m0 + tid;
        rowtok[tid] = list[e * NTOK + ((gr < cnt) ? gr : (cnt - 1))];
    }
    __syncthreads();

    int lane = tid & 63, wave = tid >> 6;
    int wm = wave & 1, wn = wave >> 1;
    int row16 = lane & 15, quad = lane >> 4;

    // staging: chunk p=tid (khalf0) and p=tid+256 (khalf1); row=(tid>>2)&63
    int rowS = (tid >> 2) & 63;
    int subS = (tid & 3) * 8;
    const unsigned short* gA  = xbf + (size_t)rowtok[rowS] * DD + subS;
    const unsigned short* gBg = Bg + (size_t)(n0 + rowS) * DD + subS;
    const unsigned short* gBu = Bu + (size_t)(n0 + rowS) * DD + subS;
    unsigned short* ldsA0 = As + wave * 512;           // + lane*16B by HW
    unsigned short* ldsA1 = As + 2048 + wave * 512;
    unsigned short* ldsG0 = Bgs + wave * 512;
    unsigned short* ldsG1 = Bgs + 2048 + wave * 512;
    unsigned short* ldsU0 = Bus + wave * 512;
    unsigned short* ldsU1 = Bus + 2048 + wave * 512;

    f32x4 accG[2][2], accU[2][2];
#pragma unroll
    for (int mi = 0; mi < 2; mi++)
#pragma unroll
        for (int ni = 0; ni < 2; ni++) {
            accG[mi][ni] = (f32x4){0.f, 0.f, 0.f, 0.f};
            accU[mi][ni] = (f32x4){0.f, 0.f, 0.f, 0.f};
        }

    for (int k0 = 0; k0 < DD; k0 += 64) {
        gl2lds16(gA + k0, ldsA0);
        gl2lds16(gA + k0 + 32, ldsA1);
        gl2lds16(gBg + k0, ldsG0);
        gl2lds16(gBg + k0 + 32, ldsG1);
        gl2lds16(gBu + k0, ldsU0);
        gl2lds16(gBu + k0 + 32, ldsU1);
        __syncthreads();

        bf16x8 a[2][2], bg[2][2], bu[2][2];
#pragma unroll
        for (int kk = 0; kk < 2; kk++) {
#pragma unroll
            for (int mi = 0; mi < 2; mi++)
                a[mi][kk] = *(const bf16x8*)(As + kk * 2048 + (wm * 32 + mi * 16 + row16) * 32 + quad * 8);
#pragma unroll
            for (int ni = 0; ni < 2; ni++) {
                bg[ni][kk] = *(const bf16x8*)(Bgs + kk * 2048 + (wn * 32 + ni * 16 + row16) * 32 + quad * 8);
                bu[ni][kk] = *(const bf16x8*)(Bus + kk * 2048 + (wn * 32 + ni * 16 + row16) * 32 + quad * 8);
            }
        }
#pragma unroll
        for (int kk = 0; kk < 2; kk++)
#pragma unroll
            for (int mi = 0; mi < 2; mi++)
#pragma unroll
                for (int ni = 0; ni < 2; ni++) {
                    accG[mi][ni] = __builtin_amdgcn_mfma_f32_16x16x32_bf16(a[mi][kk], bg[ni][kk], accG[mi][ni], 0, 0, 0);
                    accU[mi][ni] = __builtin_amdgcn_mfma_f32_16x16x32_bf16(a[mi][kk], bu[ni][kk], accU[mi][ni], 0, 0, 0);
                }
        __syncthreads();
    }

    // epilogue: silu(g)*u * route_scale -> bf16 h
#pragma unroll
    for (int mi = 0; mi < 2; mi++) {
        int grb = m0 + wm * 32 + mi * 16 + quad * 4;
#pragma unroll
        for (int r = 0; r < 4; r++) {
            int gr = grb + r;
            if (gr >= cnt) continue;
            float rs = scalebuf[e * NTOK + gr];
            size_t rowoff = ((size_t)e * NTOK + gr) * II + n0 + wn * 32;
#pragma unroll
            for (int ni = 0; ni < 2; ni++) {
                float g = accG[mi][ni][r], u = accU[mi][ni][r];
                float h = g / (1.f + __expf(-g)) * u * rs;
                hbuf[rowoff + ni * 16 + row16] = f2bf(h);
            }
        }
    }
}

// --- down GEMM: BM=64 BN=64 BK=64; atomic scatter into y -------------------
__global__ __launch_bounds__(256, 6) void down_kernel(
    const unsigned short* __restrict__ hbuf,
    const unsigned short* __restrict__ wdb,
    const int* __restrict__ count, const int* __restrict__ list,
    float* __restrict__ y)
{
    int e = blockIdx.z;
    int cnt = count[e];
    int m0 = blockIdx.x * 64;
    if (m0 >= cnt) return;
    int n0 = blockIdx.y * 64;
    const unsigned short* Bp = wdb + (size_t)e * DD * II;

    __shared__ __align__(16) unsigned short As[4096];
    __shared__ __align__(16) unsigned short Bs[4096];

    int tid = threadIdx.x;
    int lane = tid & 63, wave = tid >> 6;
    int wm = wave & 1, wn = wave >> 1;
    int row16 = lane & 15, quad = lane >> 4;

    int rowS = (tid >> 2) & 63;
    int subS = (tid & 3) * 8;
    int grS = m0 + rowS;
    int idxS = (grS < cnt) ? grS : (cnt - 1);   // clamp: garbage rows skipped in epilogue
    const unsigned short* gA = hbuf + ((size_t)e * NTOK + idxS) * II + subS;
    const unsigned short* gB = Bp + (size_t)(n0 + rowS) * II + subS;
    unsigned short* ldsA0 = As + wave * 512;
    unsigned short* ldsA1 = As + 2048 + wave * 512;
    unsigned short* ldsB0 = Bs + wave * 512;
    unsigned short* ldsB1 = Bs + 2048 + wave * 512;

    f32x4 acc[2][2];
#pragma unroll
    for (int mi = 0; mi < 2; mi++)
#pragma unroll
        for (int ni = 0; ni < 2; ni++) acc[mi][ni] = (f32x4){0.f, 0.f, 0.f, 0.f};

    for (int k0 = 0; k0 < II; k0 += 64) {
        gl2lds16(gA + k0, ldsA0);
        gl2lds16(gA + k0 + 32, ldsA1);
        gl2lds16(gB + k0, ldsB0);
        gl2lds16(gB + k0 + 32, ldsB1);
        __syncthreads();

        bf16x8 a[2][2], b[2][2];
#pragma unroll
        for (int kk = 0; kk < 2; kk++) {
#pragma unroll
            for (int mi = 0; mi < 2; mi++)
                a[mi][kk] = *(const bf16x8*)(As + kk * 2048 + (wm * 32 + mi * 16 + row16) * 32 + quad * 8);
#pragma unroll
            for (int ni = 0; ni < 2; ni++)
                b[ni][kk] = *(const bf16x8*)(Bs + kk * 2048 + (wn * 32 + ni * 16 + row16) * 32 + quad * 8);
        }
#pragma unroll
        for (int kk = 0; kk < 2; kk++)
#pragma unroll
            for (int mi = 0; mi < 2; mi++)
#pragma unroll
                for (int ni = 0; ni < 2; ni++)
                    acc[mi][ni] = __builtin_amdgcn_mfma_f32_16x16x32_bf16(a[mi][kk], b[ni][kk], acc[mi][ni], 0, 0, 0);
        __syncthreads();
    }

#pragma unroll
    for (int mi = 0; mi < 2; mi++) {
        int grb = m0 + wm * 32 + mi * 16 + quad * 4;
#pragma unroll
        for (int r = 0; r < 4; r++) {
            int gr = grb + r;
            if (gr >= cnt) continue;
            int t = list[e * NTOK + gr];
            float* yr = y + (size_t)t * DD + n0 + wn * 32;
#pragma unroll
            for (int ni = 0; ni < 2; ni++)
                unsafeAtomicAdd(yr + ni * 16 + row16, acc[mi][ni][r]);
        }
    }
}

// ======================= fallback path (round-0 kernels) ====================
__global__ __launch_bounds__(256) void gateup_fb(
    const unsigned short* __restrict__ xbf,
    const float* __restrict__ wg, const float* __restrict__ wu,
    const float* __restrict__ sgw, const float* __restrict__ suw,
    const int* __restrict__ count, const int* __restrict__ list,
    const float* __restrict__ scalebuf, unsigned short* __restrict__ hbuf)
{
    int e = blockIdx.z;
    int cnt = count[e];
    int m0 = blockIdx.x * BM;
    if (m0 >= cnt) return;
    int n0 = blockIdx.y * BN;
    const float* Bg = (e < NE) ? wg + (size_t)e * II * DD : sgw;
    const float* Bu = (e < NE) ? wu + (size_t)e * II * DD : suw;

    __shared__ __align__(16) unsigned short As[BM * LDA];
    __shared__ __align__(16) unsigned short Bgs[BN * LDA];
    __shared__ __align__(16) unsigned short Bus[BN * LDA];
    __shared__ int rowtok[BM];

    int tid = threadIdx.x;
    if (tid < BM) {
        int gr = m0 + tid;
        rowtok[tid] = (gr < cnt) ? list[e * NTOK + gr] : -1;
    }
    __syncthreads();

    int lane = tid & 63, wave = tid >> 6;
    int wm = wave >> 1, wn = wave & 1;
    int row16 = lane & 15, quad = lane >> 4;

    f32x4 accG[4][2], accU[4][2];
#pragma unroll
    for (int mi = 0; mi < 4; mi++)
#pragma unroll
        for (int ni = 0; ni < 2; ni++) {
            accG[mi][ni] = (f32x4){0.f, 0.f, 0.f, 0.f};
            accU[mi][ni] = (f32x4){0.f, 0.f, 0.f, 0.f};
        }

    for (int k0 = 0; k0 < DD; k0 += BK) {
#pragma unroll
        for (int i = 0; i < 2; i++) {
            int c = tid + 256 * i;
            int row = c >> 2, kc = (c & 3) * 8;
            int tok = rowtok[row];
            uint4 v = (tok >= 0) ? *(const uint4*)(xbf + (size_t)tok * DD + k0 + kc)
                                 : make_uint4(0u, 0u, 0u, 0u);
            *(uint4*)(As + row * LDA + kc) = v;
        }
#pragma unroll
        for (int i = 0; i < 2; i++) {
            int c = tid + 256 * i;
            int row = c >> 3, f = (c & 7) * 4;
            float4 vg = *(const float4*)(Bg + (size_t)(n0 + row) * DD + k0 + f);
            float4 vu = *(const float4*)(Bu + (size_t)(n0 + row) * DD + k0 + f);
            *(ushort4*)(Bgs + row * LDA + f) = make_ushort4(f2bf(vg.x), f2bf(vg.y), f2bf(vg.z), f2bf(vg.w));
            *(ushort4*)(Bus + row * LDA + f) = make_ushort4(f2bf(vu.x), f2bf(vu.y), f2bf(vu.z), f2bf(vu.w));
        }
        __syncthreads();

        bf16x8 af[4], bg[2], bu[2];
#pragma unroll
        for (int mi = 0; mi < 4; mi++)
            af[mi] = *(const bf16x8*)(As + (wm * 64 + mi * 16 + row16) * LDA + quad * 8);
#pragma unroll
        for (int ni = 0; ni < 2; ni++) {
            bg[ni] = *(const bf16x8*)(Bgs + (wn * 32 + ni * 16 + row16) * LDA + quad * 8);
            bu[ni] = *(const bf16x8*)(Bus + (wn * 32 + ni * 16 + row16) * LDA + quad * 8);
        }
#pragma unroll
        for (int mi = 0; mi < 4; mi++)
#pragma unroll
            for (int ni = 0; ni < 2; ni++) {
                accG[mi][ni] = __builtin_amdgcn_mfma_f32_16x16x32_bf16(af[mi], bg[ni], accG[mi][ni], 0, 0, 0);
                accU[mi][ni] = __builtin_amdgcn_mfma_f32_16x16x32_bf16(af[mi], bu[ni], accU[mi][ni], 0, 0, 0);
            }
        __syncthreads();
    }

#pragma unroll
    for (int mi = 0; mi < 4; mi++) {
        int mbase = wm * 64 + mi * 16 + quad * 4;
#pragma unroll
        for (int r = 0; r < 4; r++) {
            int gr = m0 + mbase + r;
            if (gr >= cnt) continue;
            float rs = scalebuf[e * NTOK + gr];
            size_t rowoff = ((size_t)e * NTOK + gr) * II + n0;
#pragma unroll
            for (int ni = 0; ni < 2; ni++) {
                int n = wn * 32 + ni * 16 + row16;
                float g = accG[mi][ni][r], u = accU[mi][ni][r];
                float h = g / (1.f + __expf(-g)) * u * rs;
                hbuf[rowoff + n] = f2bf(h);
            }
        }
    }
}

__global__ __launch_bounds__(256) void down_fb(
    const unsigned short* __restrict__ hbuf,
    const float* __restrict__ wd, const float* __restrict__ sdw,
    const int* __restrict__ count, const int* __restrict__ list,
    float* __restrict__ y)
{
    int e = blockIdx.z;
    int cnt = count[e];
    int m0 = blockIdx.x * BM;
    if (m0 >= cnt) return;
    int n0 = blockIdx.y * BN;
    const float* Bp = (e < NE) ? wd + (size_t)e * DD * II : sdw;

    __shared__ __align__(16) unsigned short As[BM * LDA];
    __shared__ __align__(16) unsigned short Bs[BN * LDA];

    int tid = threadIdx.x;
    int lane = tid & 63, wave = tid >> 6;
    int wm = wave >> 1, wn = wave & 1;
    int row16 = lane & 15, quad = lane >> 4;

    f32x4 acc[4][2];
#pragma unroll
    for (int mi = 0; mi < 4; mi++)
#pragma unroll
        for (int ni = 0; ni < 2; ni++) acc[mi][ni] = (f32x4){0.f, 0.f, 0.f, 0.f};

    const unsigned short* Abase = hbuf + ((size_t)e * NTOK + m0) * II;

    for (int k0 = 0; k0 < II; k0 += BK) {
#pragma unroll
        for (int i = 0; i < 2; i++) {
            int c = tid + 256 * i;
            int row = c >> 2, kc = (c & 3) * 8;
            uint4 v = (m0 + row < cnt) ? *(const uint4*)(Abase + (size_t)row * II + k0 + kc)
                                       : make_uint4(0u, 0u, 0u, 0u);
            *(uint4*)(As + row * LDA + kc) = v;
        }
#pragma unroll
        for (int i = 0; i < 2; i++) {
            int c = tid + 256 * i;
            int row = c >> 3, f = (c & 7) * 4;
            float4 v = *(const float4*)(Bp + (size_t)(n0 + row) * II + k0 + f);
            *(ushort4*)(Bs + row * LDA + f) = make_ushort4(f2bf(v.x), f2bf(v.y), f2bf(v.z), f2bf(v.w));
        }
        __syncthreads();

        bf16x8 af[4], bf[2];
#pragma unroll
        for (int mi = 0; mi < 4; mi++)
            af[mi] = *(const bf16x8*)(As + (wm * 64 + mi * 16 + row16) * LDA + quad * 8);
#pragma unroll
        for (int ni = 0; ni < 2; ni++)
            bf[ni] = *(const bf16x8*)(Bs + (wn * 32 + ni * 16 + row16) * LDA + quad * 8);
#pragma unroll
        for (int mi = 0; mi < 4; mi++)
#pragma unroll
            for (int ni = 0; ni < 2; ni++)
                acc[mi][ni] = __builtin_amdgcn_mfma_f32_16x16x32_bf16(af[mi], bf[ni], acc[mi][ni], 0, 0, 0);
        __syncthreads();
    }

#pragma unroll
    for (int mi = 0; mi < 4; mi++) {
        int mbase = wm * 64 + mi * 16 + quad * 4;
#pragma unroll
        for (int r = 0; r < 4; r++) {
            int gr = m0 + mbase + r;
            if (gr >= cnt) continue;
            int t = list[e * NTOK + gr];
#pragma unroll
            for (int ni = 0; ni < 2; ni++) {
                int n = wn * 32 + ni * 16 + row16;
                unsafeAtomicAdd(&y[(size_t)t * DD + n0 + n], acc[mi][ni][r]);
            }
        }
    }
}

extern "C" void kernel_launch(void* const* d_in, const int* in_sizes, int n_in,
                              void* d_out, int out_size, void* d_ws, size_t ws_size,
                              hipStream_t stream)
{
    const float* x    = (const float*)d_in[0];
    const float* gw   = (const float*)d_in[1];
    const float* bias = (const float*)d_in[2];
    const float* wg   = (const float*)d_in[3];
    const float* wu   = (const float*)d_in[4];
    const float* wd   = (const float*)d_in[5];
    const float* sgw  = (const float*)d_in[6];
    const float* suw  = (const float*)d_in[7];
    const float* sdw  = (const float*)d_in[8];
    float* y = (float*)d_out;

    char* ws = (char*)d_ws;
    unsigned short* xbf  = (unsigned short*)(ws + OFF_XBF);
    unsigned short* hbuf = (unsigned short*)(ws + OFF_H);
    unsigned short* wgb  = (unsigned short*)(ws + OFF_WG);
    unsigned short* wub  = (unsigned short*)(ws + OFF_WU);
    unsigned short* wdb  = (unsigned short*)(ws + OFF_WD);
    int*   list     = (int*)(ws + OFF_LIST);
    float* scalebuf = (float*)(ws + OFF_SCALE);
    int*   count    = (int*)(ws + OFF_CNT);

    bool big = (ws_size >= WS_NEED);
    if (!big) {
        list     = (int*)(ws + 36ull * MB);
        scalebuf = (float*)(ws + 36ull * MB + 4ull * NEXP * NTOK);
        count    = (int*)(ws + 36ull * MB + 8ull * NEXP * NTOK);
    }

    hipMemsetAsync(d_out, 0, (size_t)NTOK * DD * sizeof(float), stream);
    hipMemsetAsync(count, 0, NEXP * sizeof(int), stream);

    prep_kernel<<<dim3(NTOK * DD / 4 / 256), 256, 0, stream>>>(x, xbf, list, scalebuf, count);
    routing_kernel<<<dim3(NTOK), 64, 0, stream>>>(x, gw, bias, count, list, scalebuf);

    if (big) {
        wconv_kernel<<<dim3((unsigned)((size_t)NEXP * II * DD / 4 / 256), 3), 256, 0, stream>>>(
            wg, wu, wd, sgw, suw, sdw, wgb, wub, wdb);
        gateup_kernel<<<dim3(16, 16, NEXP), 256, 0, stream>>>(
            xbf, wgb, wub, count, list, scalebuf, hbuf);
        down_kernel<<<dim3(16, 16, NEXP), 256, 0, stream>>>(
            hbuf, wdb, count, list, y);
    } else {
        gateup_fb<<<dim3(NTOK / BM, II / BN, NEXP), 256, 0, stream>>>(
            xbf, wg, wu, sgw, suw, count, list, scalebuf, hbuf);
        down_fb<<<dim3(NTOK / BM, DD / BN, NEXP), 256, 0, stream>>>(
            hbuf, wd, sdw, count, list, y);
    }
}

// Round 6
// 473.356 us; speedup vs baseline: 1.6690x; 1.1059x over previous
//
#include <hip/hip_runtime.h>
#include <hip/hip_bf16.h>

// ---------------------------------------------------------------------------
// AfmoE MoE: routing (sigmoid top-8) + 16 routed SwiGLU experts + shared
// expert as expert #16 via gather lists.
// Round 5: XCD-swizzled 1-D grid (all M-tiles of one (expert,n0) weight tile
// on one XCD -> weights fetched from HBM once, then L2-local) + BK=128
// (half the barrier drains, 32 MFMA per drain).
// ---------------------------------------------------------------------------

typedef __attribute__((ext_vector_type(8))) short bf16x8;
typedef __attribute__((ext_vector_type(4))) float f32x4;

#define NTOK 1024   // B*S
#define DD   1024   // hidden
#define II   1024   // intermediate (same for shared)
#define NE   16     // routed experts
#define NEXP 17     // + shared expert as index 16
#define KSEL 8
#define RSCALE 2.826f

// fallback-path tiling
#define BM 128
#define BN 64
#define BK 32
#define LDA 40

// workspace layout (bytes)
#define MB (1024ull*1024ull)
#define OFF_XBF   0ull                         // ushort[NTOK*DD]          2 MiB
#define OFF_H     (2ull*MB)                    // ushort[NEXP*NTOK*II]    34 MiB
#define OFF_WG    (36ull*MB)                   // ushort[NEXP*II*DD]      34 MiB
#define OFF_WU    (70ull*MB)                   // ushort[NEXP*II*DD]      34 MiB
#define OFF_WD    (104ull*MB)                  // ushort[NEXP*DD*II]      34 MiB
#define OFF_LIST  (138ull*MB)                  // int[NEXP*NTOK]
#define OFF_SCALE (OFF_LIST + 4ull*NEXP*NTOK)  // float[NEXP*NTOK]
#define OFF_CNT   (OFF_SCALE + 4ull*NEXP*NTOK) // int[NEXP]
#define WS_NEED   (OFF_CNT + 4096ull)

__device__ __forceinline__ unsigned short f2bf(float f) {
    union { __hip_bfloat16 h; unsigned short u; } c;
    c.h = __float2bfloat16(f);
    return c.u;
}

__device__ __forceinline__ void gl2lds16(const unsigned short* g, unsigned short* l) {
    __builtin_amdgcn_global_load_lds(
        (const __attribute__((address_space(1))) void*)g,
        (__attribute__((address_space(3))) void*)l, 16, 0, 0);
}

// --- convert x to bf16; init shared-expert list/scale/count -----------------
__global__ __launch_bounds__(256) void prep_kernel(
    const float* __restrict__ x, unsigned short* __restrict__ xbf,
    int* __restrict__ list, float* __restrict__ scalebuf, int* __restrict__ count)
{
    int idx = blockIdx.x * 256 + threadIdx.x;
    float4 v = ((const float4*)x)[idx];
    ((ushort4*)xbf)[idx] = make_ushort4(f2bf(v.x), f2bf(v.y), f2bf(v.z), f2bf(v.w));
    if (idx < NTOK) { list[NE * NTOK + idx] = idx; scalebuf[NE * NTOK + idx] = 1.0f; }
    if (idx == 0) count[NE] = NTOK;
}

// --- convert all expert weights fp32 -> bf16 pools -------------------------
__global__ __launch_bounds__(256) void wconv_kernel(
    const float* __restrict__ wg, const float* __restrict__ wu, const float* __restrict__ wd,
    const float* __restrict__ sgw, const float* __restrict__ suw, const float* __restrict__ sdw,
    unsigned short* __restrict__ wgb, unsigned short* __restrict__ wub,
    unsigned short* __restrict__ wdb)
{
    size_t i4 = (size_t)blockIdx.x * 256 + threadIdx.x;
    const size_t ROUTED4 = (size_t)NE * II * DD / 4;
    int p = blockIdx.y;
    const float* rsrc = (p == 0) ? wg : (p == 1) ? wu : wd;
    const float* ssrc = (p == 0) ? sgw : (p == 1) ? suw : sdw;
    unsigned short* dst = (p == 0) ? wgb : (p == 1) ? wub : wdb;
    const float* src = (i4 < ROUTED4) ? rsrc + 4 * i4 : ssrc + 4 * (i4 - ROUTED4);
    float4 v = *(const float4*)src;
    ((ushort4*)dst)[i4] = make_ushort4(f2bf(v.x), f2bf(v.y), f2bf(v.z), f2bf(v.w));
}

// --- routing: one wave per token -------------------------------------------
__global__ __launch_bounds__(64) void routing_kernel(
    const float* __restrict__ x, const float* __restrict__ gw,
    const float* __restrict__ bias, int* __restrict__ count,
    int* __restrict__ list, float* __restrict__ scalebuf)
{
    int t = blockIdx.x, lane = threadIdx.x;
    float acc[NE];
#pragma unroll
    for (int e = 0; e < NE; e++) acc[e] = 0.f;
    const float* xr = x + (size_t)t * DD;
    for (int i = 0; i < DD / 64; i++) {
        float xv = xr[lane + 64 * i];
#pragma unroll
        for (int e = 0; e < NE; e++) acc[e] += xv * gw[e * DD + lane + 64 * i];
    }
#pragma unroll
    for (int e = 0; e < NE; e++) {
        float v = acc[e];
        for (int off = 32; off > 0; off >>= 1) v += __shfl_xor(v, off, 64);
        acc[e] = v;
    }
    if (lane == 0) {
        float sc[NE], sel[NE];
#pragma unroll
        for (int e = 0; e < NE; e++) {
            sc[e] = 1.f / (1.f + expf(-acc[e]));
            sel[e] = sc[e] + bias[e];
        }
        bool used[NE] = {};
        int inds[KSEL];
        float ssum = 0.f;
        for (int k = 0; k < KSEL; k++) {
            float best = -1e30f; int bi = 0;
            for (int e = 0; e < NE; e++)
                if (!used[e] && sel[e] > best) { best = sel[e]; bi = e; }
            used[bi] = true; inds[k] = bi; ssum += sc[bi];
        }
        float inv = RSCALE / ssum;
        for (int k = 0; k < KSEL; k++) {
            int e = inds[k];
            int pos = atomicAdd(&count[e], 1);
            list[e * NTOK + pos] = t;
            scalebuf[e * NTOK + pos] = sc[e] * inv;
        }
    }
}

// --- fused gate+up GEMM: BM=64 BN=64 BK=128, XCD-swizzled 1-D grid ---------
// grid 4352 = 17 experts x 16 n-tiles x 16 m-tiles. slot->(e,n0,m0) decode
// puts all 16 m-tiles of one (e,n0) on one XCD (slot&7) for L2 weight reuse.
__global__ __launch_bounds__(256, 3) void gateup_kernel(
    const unsigned short* __restrict__ xbf,
    const unsigned short* __restrict__ wgb, const unsigned short* __restrict__ wub,
    const int* __restrict__ count, const int* __restrict__ list,
    const float* __restrict__ scalebuf, unsigned short* __restrict__ hbuf)
{
    int s = blockIdx.x;
    int xcd = s & 7, t = s >> 3;
    int g = xcd + 8 * (t >> 4);          // (e,n0) group, g%8 == xcd
    int e = g >> 4;
    int n0 = (g & 15) * 64;
    int m0 = (t & 15) * 64;
    int cnt = count[e];
    if (m0 >= cnt) return;
    const unsigned short* Bg = wgb + (size_t)e * II * DD;
    const unsigned short* Bu = wub + (size_t)e * II * DD;

    // LDS: [kq 0..3][row 0..63][32 elems] -> 8192 ushorts (16 KB) per tile
    __shared__ __align__(16) unsigned short As[8192];
    __shared__ __align__(16) unsigned short Bgs[8192];
    __shared__ __align__(16) unsigned short Bus[8192];
    __shared__ int rowtok[64];

    int tid = threadIdx.x;
    if (tid < 64) {
        int gr = m0 + tid;
        rowtok[tid] = list[e * NTOK + ((gr < cnt) ? gr : (cnt - 1))];
    }
    __syncthreads();

    int lane = tid & 63, wave = tid >> 6;
    int wm = wave & 1, wn = wave >> 1;
    int row16 = lane & 15, quad = lane >> 4;

    // staging: thread stages 4 chunks (one per kq); row=(tid>>2)&63
    int rowS = (tid >> 2) & 63;
    int subS = (tid & 3) * 8;
    const unsigned short* gA  = xbf + (size_t)rowtok[rowS] * DD + subS;
    const unsigned short* gBg = Bg + (size_t)(n0 + rowS) * DD + subS;
    const unsigned short* gBu = Bu + (size_t)(n0 + rowS) * DD + subS;

    f32x4 accG[2][2], accU[2][2];
#pragma unroll
    for (int mi = 0; mi < 2; mi++)
#pragma unroll
        for (int ni = 0; ni < 2; ni++) {
            accG[mi][ni] = (f32x4){0.f, 0.f, 0.f, 0.f};
            accU[mi][ni] = (f32x4){0.f, 0.f, 0.f, 0.f};
        }

    for (int k0 = 0; k0 < DD; k0 += 128) {
#pragma unroll
        for (int q = 0; q < 4; q++) {
            gl2lds16(gA + k0 + q * 32, As + q * 2048 + wave * 512);
            gl2lds16(gBg + k0 + q * 32, Bgs + q * 2048 + wave * 512);
            gl2lds16(gBu + k0 + q * 32, Bus + q * 2048 + wave * 512);
        }
        __syncthreads();

#pragma unroll
        for (int kk = 0; kk < 4; kk++) {
            bf16x8 a[2], bg[2], bu[2];
#pragma unroll
            for (int mi = 0; mi < 2; mi++)
                a[mi] = *(const bf16x8*)(As + kk * 2048 + (wm * 32 + mi * 16 + row16) * 32 + quad * 8);
#pragma unroll
            for (int ni = 0; ni < 2; ni++) {
                bg[ni] = *(const bf16x8*)(Bgs + kk * 2048 + (wn * 32 + ni * 16 + row16) * 32 + quad * 8);
                bu[ni] = *(const bf16x8*)(Bus + kk * 2048 + (wn * 32 + ni * 16 + row16) * 32 + quad * 8);
            }
#pragma unroll
            for (int mi = 0; mi < 2; mi++)
#pragma unroll
                for (int ni = 0; ni < 2; ni++) {
                    accG[mi][ni] = __builtin_amdgcn_mfma_f32_16x16x32_bf16(a[mi], bg[ni], accG[mi][ni], 0, 0, 0);
                    accU[mi][ni] = __builtin_amdgcn_mfma_f32_16x16x32_bf16(a[mi], bu[ni], accU[mi][ni], 0, 0, 0);
                }
        }
        __syncthreads();
    }

    // epilogue: silu(g)*u * route_scale -> bf16 h
#pragma unroll
    for (int mi = 0; mi < 2; mi++) {
        int grb = m0 + wm * 32 + mi * 16 + quad * 4;
#pragma unroll
        for (int r = 0; r < 4; r++) {
            int gr = grb + r;
            if (gr >= cnt) continue;
            float rs = scalebuf[e * NTOK + gr];
            size_t rowoff = ((size_t)e * NTOK + gr) * II + n0 + wn * 32;
#pragma unroll
            for (int ni = 0; ni < 2; ni++) {
                float g2 = accG[mi][ni][r], u = accU[mi][ni][r];
                float h = g2 / (1.f + __expf(-g2)) * u * rs;
                hbuf[rowoff + ni * 16 + row16] = f2bf(h);
            }
        }
    }
}

// --- down GEMM: BM=64 BN=64 BK=128, XCD-swizzled; atomic scatter into y ----
__global__ __launch_bounds__(256, 5) void down_kernel(
    const unsigned short* __restrict__ hbuf,
    const unsigned short* __restrict__ wdb,
    const int* __restrict__ count, const int* __restrict__ list,
    float* __restrict__ y)
{
    int s = blockIdx.x;
    int xcd = s & 7, t = s >> 3;
    int g = xcd + 8 * (t >> 4);
    int e = g >> 4;
    int n0 = (g & 15) * 64;
    int m0 = (t & 15) * 64;
    int cnt = count[e];
    if (m0 >= cnt) return;
    const unsigned short* Bp = wdb + (size_t)e * DD * II;

    __shared__ __align__(16) unsigned short As[8192];
    __shared__ __align__(16) unsigned short Bs[8192];

    int tid = threadIdx.x;
    int lane = tid & 63, wave = tid >> 6;
    int wm = wave & 1, wn = wave >> 1;
    int row16 = lane & 15, quad = lane >> 4;

    int rowS = (tid >> 2) & 63;
    int subS = (tid & 3) * 8;
    int grS = m0 + rowS;
    int idxS = (grS < cnt) ? grS : (cnt - 1);   // clamp: garbage rows skipped in epilogue
    const unsigned short* gA = hbuf + ((size_t)e * NTOK + idxS) * II + subS;
    const unsigned short* gB = Bp + (size_t)(n0 + rowS) * II + subS;

    f32x4 acc[2][2];
#pragma unroll
    for (int mi = 0; mi < 2; mi++)
#pragma unroll
        for (int ni = 0; ni < 2; ni++) acc[mi][ni] = (f32x4){0.f, 0.f, 0.f, 0.f};

    for (int k0 = 0; k0 < II; k0 += 128) {
#pragma unroll
        for (int q = 0; q < 4; q++) {
            gl2lds16(gA + k0 + q * 32, As + q * 2048 + wave * 512);
            gl2lds16(gB + k0 + q * 32, Bs + q * 2048 + wave * 512);
        }
        __syncthreads();

#pragma unroll
        for (int kk = 0; kk < 4; kk++) {
            bf16x8 a[2], b[2];
#pragma unroll
            for (int mi = 0; mi < 2; mi++)
                a[mi] = *(const bf16x8*)(As + kk * 2048 + (wm * 32 + mi * 16 + row16) * 32 + quad * 8);
#pragma unroll
            for (int ni = 0; ni < 2; ni++)
                b[ni] = *(const bf16x8*)(Bs + kk * 2048 + (wn * 32 + ni * 16 + row16) * 32 + quad * 8);
#pragma unroll
            for (int mi = 0; mi < 2; mi++)
#pragma unroll
                for (int ni = 0; ni < 2; ni++)
                    acc[mi][ni] = __builtin_amdgcn_mfma_f32_16x16x32_bf16(a[mi], b[ni], acc[mi][ni], 0, 0, 0);
        }
        __syncthreads();
    }

#pragma unroll
    for (int mi = 0; mi < 2; mi++) {
        int grb = m0 + wm * 32 + mi * 16 + quad * 4;
#pragma unroll
        for (int r = 0; r < 4; r++) {
            int gr = grb + r;
            if (gr >= cnt) continue;
            int tk = list[e * NTOK + gr];
            float* yr = y + (size_t)tk * DD + n0 + wn * 32;
#pragma unroll
            for (int ni = 0; ni < 2; ni++)
                unsafeAtomicAdd(yr + ni * 16 + row16, acc[mi][ni][r]);
        }
    }
}

// ======================= fallback path (round-0 kernels) ====================
__global__ __launch_bounds__(256) void gateup_fb(
    const unsigned short* __restrict__ xbf,
    const float* __restrict__ wg, const float* __restrict__ wu,
    const float* __restrict__ sgw, const float* __restrict__ suw,
    const int* __restrict__ count, const int* __restrict__ list,
    const float* __restrict__ scalebuf, unsigned short* __restrict__ hbuf)
{
    int e = blockIdx.z;
    int cnt = count[e];
    int m0 = blockIdx.x * BM;
    if (m0 >= cnt) return;
    int n0 = blockIdx.y * BN;
    const float* Bg = (e < NE) ? wg + (size_t)e * II * DD : sgw;
    const float* Bu = (e < NE) ? wu + (size_t)e * II * DD : suw;

    __shared__ __align__(16) unsigned short As[BM * LDA];
    __shared__ __align__(16) unsigned short Bgs[BN * LDA];
    __shared__ __align__(16) unsigned short Bus[BN * LDA];
    __shared__ int rowtok[BM];

    int tid = threadIdx.x;
    if (tid < BM) {
        int gr = m0 + tid;
        rowtok[tid] = (gr < cnt) ? list[e * NTOK + gr] : -1;
    }
    __syncthreads();

    int lane = tid & 63, wave = tid >> 6;
    int wm = wave >> 1, wn = wave & 1;
    int row16 = lane & 15, quad = lane >> 4;

    f32x4 accG[4][2], accU[4][2];
#pragma unroll
    for (int mi = 0; mi < 4; mi++)
#pragma unroll
        for (int ni = 0; ni < 2; ni++) {
            accG[mi][ni] = (f32x4){0.f, 0.f, 0.f, 0.f};
            accU[mi][ni] = (f32x4){0.f, 0.f, 0.f, 0.f};
        }

    for (int k0 = 0; k0 < DD; k0 += BK) {
#pragma unroll
        for (int i = 0; i < 2; i++) {
            int c = tid + 256 * i;
            int row = c >> 2, kc = (c & 3) * 8;
            int tok = rowtok[row];
            uint4 v = (tok >= 0) ? *(const uint4*)(xbf + (size_t)tok * DD + k0 + kc)
                                 : make_uint4(0u, 0u, 0u, 0u);
            *(uint4*)(As + row * LDA + kc) = v;
        }
#pragma unroll
        for (int i = 0; i < 2; i++) {
            int c = tid + 256 * i;
            int row = c >> 3, f = (c & 7) * 4;
            float4 vg = *(const float4*)(Bg + (size_t)(n0 + row) * DD + k0 + f);
            float4 vu = *(const float4*)(Bu + (size_t)(n0 + row) * DD + k0 + f);
            *(ushort4*)(Bgs + row * LDA + f) = make_ushort4(f2bf(vg.x), f2bf(vg.y), f2bf(vg.z), f2bf(vg.w));
            *(ushort4*)(Bus + row * LDA + f) = make_ushort4(f2bf(vu.x), f2bf(vu.y), f2bf(vu.z), f2bf(vu.w));
        }
        __syncthreads();

        bf16x8 af[4], bg[2], bu[2];
#pragma unroll
        for (int mi = 0; mi < 4; mi++)
            af[mi] = *(const bf16x8*)(As + (wm * 64 + mi * 16 + row16) * LDA + quad * 8);
#pragma unroll
        for (int ni = 0; ni < 2; ni++) {
            bg[ni] = *(const bf16x8*)(Bgs + (wn * 32 + ni * 16 + row16) * LDA + quad * 8);
            bu[ni] = *(const bf16x8*)(Bus + (wn * 32 + ni * 16 + row16) * LDA + quad * 8);
        }
#pragma unroll
        for (int mi = 0; mi < 4; mi++)
#pragma unroll
            for (int ni = 0; ni < 2; ni++) {
                accG[mi][ni] = __builtin_amdgcn_mfma_f32_16x16x32_bf16(af[mi], bg[ni], accG[mi][ni], 0, 0, 0);
                accU[mi][ni] = __builtin_amdgcn_mfma_f32_16x16x32_bf16(af[mi], bu[ni], accU[mi][ni], 0, 0, 0);
            }
        __syncthreads();
    }

#pragma unroll
    for (int mi = 0; mi < 4; mi++) {
        int mbase = wm * 64 + mi * 16 + quad * 4;
#pragma unroll
        for (int r = 0; r < 4; r++) {
            int gr = m0 + mbase + r;
            if (gr >= cnt) continue;
            float rs = scalebuf[e * NTOK + gr];
            size_t rowoff = ((size_t)e * NTOK + gr) * II + n0;
#pragma unroll
            for (int ni = 0; ni < 2; ni++) {
                int n = wn * 32 + ni * 16 + row16;
                float g = accG[mi][ni][r], u = accU[mi][ni][r];
                float h = g / (1.f + __expf(-g)) * u * rs;
                hbuf[rowoff + n] = f2bf(h);
            }
        }
    }
}

__global__ __launch_bounds__(256) void down_fb(
    const unsigned short* __restrict__ hbuf,
    const float* __restrict__ wd, const float* __restrict__ sdw,
    const int* __restrict__ count, const int* __restrict__ list,
    float* __restrict__ y)
{
    int e = blockIdx.z;
    int cnt = count[e];
    int m0 = blockIdx.x * BM;
    if (m0 >= cnt) return;
    int n0 = blockIdx.y * BN;
    const float* Bp = (e < NE) ? wd + (size_t)e * DD * II : sdw;

    __shared__ __align__(16) unsigned short As[BM * LDA];
    __shared__ __align__(16) unsigned short Bs[BN * LDA];

    int tid = threadIdx.x;
    int lane = tid & 63, wave = tid >> 6;
    int wm = wave >> 1, wn = wave & 1;
    int row16 = lane & 15, quad = lane >> 4;

    f32x4 acc[4][2];
#pragma unroll
    for (int mi = 0; mi < 4; mi++)
#pragma unroll
        for (int ni = 0; ni < 2; ni++) acc[mi][ni] = (f32x4){0.f, 0.f, 0.f, 0.f};

    const unsigned short* Abase = hbuf + ((size_t)e * NTOK + m0) * II;

    for (int k0 = 0; k0 < II; k0 += BK) {
#pragma unroll
        for (int i = 0; i < 2; i++) {
            int c = tid + 256 * i;
            int row = c >> 2, kc = (c & 3) * 8;
            uint4 v = (m0 + row < cnt) ? *(const uint4*)(Abase + (size_t)row * II + k0 + kc)
                                       : make_uint4(0u, 0u, 0u, 0u);
            *(uint4*)(As + row * LDA + kc) = v;
        }
#pragma unroll
        for (int i = 0; i < 2; i++) {
            int c = tid + 256 * i;
            int row = c >> 3, f = (c & 7) * 4;
            float4 v = *(const float4*)(Bp + (size_t)(n0 + row) * II + k0 + f);
            *(ushort4*)(Bs + row * LDA + f) = make_ushort4(f2bf(v.x), f2bf(v.y), f2bf(v.z), f2bf(v.w));
        }
        __syncthreads();

        bf16x8 af[4], bf[2];
#pragma unroll
        for (int mi = 0; mi < 4; mi++)
            af[mi] = *(const bf16x8*)(As + (wm * 64 + mi * 16 + row16) * LDA + quad * 8);
#pragma unroll
        for (int ni = 0; ni < 2; ni++)
            bf[ni] = *(const bf16x8*)(Bs + (wn * 32 + ni * 16 + row16) * LDA + quad * 8);
#pragma unroll
        for (int mi = 0; mi < 4; mi++)
#pragma unroll
            for (int ni = 0; ni < 2; ni++)
                acc[mi][ni] = __builtin_amdgcn_mfma_f32_16x16x32_bf16(af[mi], bf[ni], acc[mi][ni], 0, 0, 0);
        __syncthreads();
    }

#pragma unroll
    for (int mi = 0; mi < 4; mi++) {
        int mbase = wm * 64 + mi * 16 + quad * 4;
#pragma unroll
        for (int r = 0; r < 4; r++) {
            int gr = m0 + mbase + r;
            if (gr >= cnt) continue;
            int t = list[e * NTOK + gr];
#pragma unroll
            for (int ni = 0; ni < 2; ni++) {
                int n = wn * 32 + ni * 16 + row16;
                unsafeAtomicAdd(&y[(size_t)t * DD + n0 + n], acc[mi][ni][r]);
            }
        }
    }
}

extern "C" void kernel_launch(void* const* d_in, const int* in_sizes, int n_in,
                              void* d_out, int out_size, void* d_ws, size_t ws_size,
                              hipStream_t stream)
{
    const float* x    = (const float*)d_in[0];
    const float* gw   = (const float*)d_in[1];
    const float* bias = (const float*)d_in[2];
    const float* wg   = (const float*)d_in[3];
    const float* wu   = (const float*)d_in[4];
    const float* wd   = (const float*)d_in[5];
    const float* sgw  = (const float*)d_in[6];
    const float* suw  = (const float*)d_in[7];
    const float* sdw  = (const float*)d_in[8];
    float* y = (float*)d_out;

    char* ws = (char*)d_ws;
    unsigned short* xbf  = (unsigned short*)(ws + OFF_XBF);
    unsigned short* hbuf = (unsigned short*)(ws + OFF_H);
    unsigned short* wgb  = (unsigned short*)(ws + OFF_WG);
    unsigned short* wub  = (unsigned short*)(ws + OFF_WU);
    unsigned short* wdb  = (unsigned short*)(ws + OFF_WD);
    int*   list     = (int*)(ws + OFF_LIST);
    float* scalebuf = (float*)(ws + OFF_SCALE);
    int*   count    = (int*)(ws + OFF_CNT);

    bool big = (ws_size >= WS_NEED);
    if (!big) {
        list     = (int*)(ws + 36ull * MB);
        scalebuf = (float*)(ws + 36ull * MB + 4ull * NEXP * NTOK);
        count    = (int*)(ws + 36ull * MB + 8ull * NEXP * NTOK);
    }

    hipMemsetAsync(d_out, 0, (size_t)NTOK * DD * sizeof(float), stream);
    hipMemsetAsync(count, 0, NEXP * sizeof(int), stream);

    prep_kernel<<<dim3(NTOK * DD / 4 / 256), 256, 0, stream>>>(x, xbf, list, scalebuf, count);
    routing_kernel<<<dim3(NTOK), 64, 0, stream>>>(x, gw, bias, count, list, scalebuf);

    if (big) {
        wconv_kernel<<<dim3((unsigned)((size_t)NEXP * II * DD / 4 / 256), 3), 256, 0, stream>>>(
            wg, wu, wd, sgw, suw, sdw, wgb, wub, wdb);
        gateup_kernel<<<dim3(NEXP * 16 * 16), 256, 0, stream>>>(
            xbf, wgb, wub, count, list, scalebuf, hbuf);
        down_kernel<<<dim3(NEXP * 16 * 16), 256, 0, stream>>>(
            hbuf, wdb, count, list, y);
    } else {
        gateup_fb<<<dim3(NTOK / BM, II / BN, NEXP), 256, 0, stream>>>(
            xbf, wg, wu, sgw, suw, count, list, scalebuf, hbuf);
        down_fb<<<dim3(NTOK / BM, DD / BN, NEXP), 256, 0, stream>>>(
            hbuf, wd, sdw, count, list, y);
    }
}